// Round 8
// baseline (356.680 us; speedup 1.0000x reference)
//
#include <hip/hip_runtime.h>
#include <cstdint>

// EncoderBlock: pre-LN transformer block. B=2,S=2048,D=768,F=3072,H=12,dk=64.
// bf16 MFMA 16x16x32; fp32 accumulate.
// R8: occupancy attack. GEMMs TM=64 (grids 1536 = 6 blocks/CU, lb(256,6));
//     attention: V^T frags loaded global->reg (A-layout is 16B/lane contiguous),
//     vts LDS dropped (34.4KB -> 4 blocks/CU), kv-split 4 (grid 1536), lb(256,4).

typedef __bf16 bf16;
typedef __bf16 bf16x4 __attribute__((ext_vector_type(4)));
typedef __bf16 bf16x8 __attribute__((ext_vector_type(8)));
typedef float f32x4 __attribute__((ext_vector_type(4)));

#define DEV __device__ __forceinline__

DEV f32x4 mfma16(bf16x8 a, bf16x8 b, f32x4 c) {
    return __builtin_amdgcn_mfma_f32_16x16x32_bf16(a, b, c, 0, 0, 0);
}

typedef unsigned int u32;
typedef const u32 __attribute__((address_space(1))) gu32;
typedef u32 __attribute__((address_space(3))) lu32;

DEV void gl_lds16(const void* g, void* l) {
    __builtin_amdgcn_global_load_lds((gu32*)(uintptr_t)g,
                                     (lu32*)(u32)(uintptr_t)l, 16, 0, 0);
}

// ---------------- all weight transposes (fp32->bf16, [K][N]->[N][K]) ----------------
__global__ void __launch_bounds__(256)
transpose_all(const float* __restrict__ wq, const float* __restrict__ wk,
              const float* __restrict__ wv, const float* __restrict__ wo,
              const float* __restrict__ w1, const float* __restrict__ w2,
              bf16* __restrict__ qkvT, bf16* __restrict__ woT,
              bf16* __restrict__ w1T, bf16* __restrict__ w2T) {
    __shared__ float t[32][33];
    int id = blockIdx.x;
    const float* in;
    bf16* out;
    int K, N, bx, by;
    if (id < 2304) {
        int mat = id / 576, r = id - mat * 576;
        K = 768; N = 768; bx = r % 24; by = r / 24;
        in = mat == 0 ? wq : mat == 1 ? wk : mat == 2 ? wv : wo;
        out = mat == 3 ? woT : qkvT + (size_t)mat * 768 * 768;
    } else if (id < 4608) {
        int r = id - 2304;
        K = 768; N = 3072; bx = r % 96; by = r / 96;
        in = w1; out = w1T;
    } else {
        int r = id - 4608;
        K = 3072; N = 768; bx = r % 24; by = r / 24;
        in = w2; out = w2T;
    }
    const int tx = threadIdx.x & 31, ty = threadIdx.x >> 5;
    const int n0 = bx * 32, k0 = by * 32;
#pragma unroll
    for (int i = 0; i < 32; i += 8)
        t[ty + i][tx] = in[(size_t)(k0 + ty + i) * N + n0 + tx];
    __syncthreads();
#pragma unroll
    for (int i = 0; i < 32; i += 8)
        out[(size_t)(n0 + ty + i) * K + k0 + tx] = (bf16)t[tx][ty + i];
}

// V [bh][2048][64] -> VT [bh][64][2048]
__global__ void __launch_bounds__(256)
vtrans_kernel(const bf16* __restrict__ V, bf16* __restrict__ VT) {
    __shared__ bf16 t[64 * 72];
    const int tid = threadIdx.x;
    const int s0 = blockIdx.x * 64;
    const bf16* Vb = V + (size_t)blockIdx.y * 2048 * 64;
    bf16* Tb = VT + (size_t)blockIdx.y * 64 * 2048;
#pragma unroll
    for (int cc = 0; cc < 2; ++cc) {
        int c = tid + cc * 256;
        int r = c >> 3, off = (c & 7) * 8;
        *(bf16x8*)&t[r * 72 + off] = *(const bf16x8*)(Vb + (size_t)(s0 + r) * 64 + off);
    }
    __syncthreads();
#pragma unroll
    for (int cc = 0; cc < 2; ++cc) {
        int oc = tid + cc * 256;
        int d = oc & 63, sg = oc >> 6;
        bf16x8 e;
#pragma unroll
        for (int j = 0; j < 8; ++j) e[j] = t[(sg * 8 + j) * 72 + d];
        *(bf16x8*)(Tb + (size_t)d * 2048 + s0 + sg * 8) = e;
    }
}

// ---------------- layernorm (ddof=1) ----------------
__global__ void __launch_bounds__(256)
ln_kernel(const float* __restrict__ X, bf16* __restrict__ Y,
          const float* __restrict__ alpha, const float* __restrict__ beta) {
    __shared__ float red[8];
    const int row = blockIdx.x;
    const int tid = threadIdx.x;
    const float* xr = X + (size_t)row * 768;
    float x0 = xr[tid], x1 = xr[tid + 256], x2 = xr[tid + 512];
    float s = x0 + x1 + x2, sq = x0 * x0 + x1 * x1 + x2 * x2;
#pragma unroll
    for (int off = 32; off >= 1; off >>= 1) {
        s += __shfl_xor(s, off, 64);
        sq += __shfl_xor(sq, off, 64);
    }
    const int wave = tid >> 6;
    if ((tid & 63) == 0) { red[wave] = s; red[4 + wave] = sq; }
    __syncthreads();
    s = red[0] + red[1] + red[2] + red[3];
    sq = red[4] + red[5] + red[6] + red[7];
    float mean = s * (1.f / 768.f);
    float var = (sq - 768.f * mean * mean) * (1.f / 767.f);
    float a = alpha[0] * rsqrtf(var + 1e-6f), bb = beta[0];
    bf16* yr = Y + (size_t)row * 768;
    yr[tid]       = (bf16)((x0 - mean) * a + bb);
    yr[tid + 256] = (bf16)((x1 - mean) * a + bb);
    yr[tid + 512] = (bf16)((x2 - mean) * a + bb);
}

// combine OPROJ split-K bf16 partials + bias + residual, then LN2
__global__ void __launch_bounds__(256)
combine_ln2(const bf16* __restrict__ P, const float* __restrict__ bo,
            const float* __restrict__ X, float* __restrict__ X2,
            bf16* __restrict__ XN,
            const float* __restrict__ alpha, const float* __restrict__ beta) {
    __shared__ float red[8];
    const int row = blockIdx.x;
    const int tid = threadIdx.x;
    const size_t base = (size_t)row * 768;
    const bf16* p0 = P + base;
    const bf16* p1 = P + (size_t)4096 * 768 + base;
    float v[3];
#pragma unroll
    for (int i = 0; i < 3; ++i) {
        int c = tid + i * 256;
        v[i] = (float)p0[c] + (float)p1[c] + bo[c] + X[base + c];
        X2[base + c] = v[i];
    }
    float s = v[0] + v[1] + v[2];
    float sq = v[0] * v[0] + v[1] * v[1] + v[2] * v[2];
#pragma unroll
    for (int off = 32; off >= 1; off >>= 1) {
        s += __shfl_xor(s, off, 64);
        sq += __shfl_xor(sq, off, 64);
    }
    const int wave = tid >> 6;
    if ((tid & 63) == 0) { red[wave] = s; red[4 + wave] = sq; }
    __syncthreads();
    s = red[0] + red[1] + red[2] + red[3];
    sq = red[4] + red[5] + red[6] + red[7];
    float mean = s * (1.f / 768.f);
    float var = (sq - 768.f * mean * mean) * (1.f / 767.f);
    float a = alpha[0] * rsqrtf(var + 1e-6f), bb = beta[0];
#pragma unroll
    for (int i = 0; i < 3; ++i)
        XN[base + tid + i * 256] = (bf16)((v[i] - mean) * a + bb);
}

__global__ void __launch_bounds__(256)
ffn2_combine(const bf16* __restrict__ P, const float* __restrict__ b2,
             const float* __restrict__ X2, float* __restrict__ OUT) {
    const size_t i4 = (size_t)blockIdx.x * 256 + threadIdx.x;
    const size_t f = i4 * 4;
    const int col = (int)(f % 768);
    bf16x4 a = *(const bf16x4*)(P + f);
    bf16x4 b = *(const bf16x4*)(P + (size_t)4096 * 768 + f);
    f32x4 x = *(const f32x4*)(X2 + f);
    f32x4 bi = *(const f32x4*)(b2 + col);
    f32x4 o;
#pragma unroll
    for (int i = 0; i < 4; ++i) o[i] = (float)a[i] + (float)b[i] + x[i] + bi[i];
    *(f32x4*)(OUT + f) = o;
}

// ---------------- GEMM: TM=64, prefetch dbuf, XCD-aware swizzle ----------------
// Flat grid = GX * Tiles (Tiles % 8 == 0). c=blockIdx&7 (XCD), s=blockIdx>>3:
// xb = s%GX (n-tile), tile = (s/GX)*8+c. MODE 4: mt=tile>>1, zz=tile&1.
// Waves 2x2 over (64, TN): wm=(wave>>1)*32, wn=(wave&1)*(TN/2).
// MODE 0: QKV -> scatter bf16 q/k/v (+biases; q pre-scaled by 0.125*log2e)
// MODE 2: FFN1 -> bf16 relu(acc + b1)
// MODE 4: split-K partial -> bf16 out0[z][row][col]
template <int MODE, int TN, int GX>
__global__ void __launch_bounds__(256, 6)
gemm_kernel(const bf16* __restrict__ A, const bf16* __restrict__ BT,
            int K, int N,
            const float* __restrict__ bias0, const float* __restrict__ bias1,
            const float* __restrict__ bias2,
            void* __restrict__ out0, void* __restrict__ out1, void* __restrict__ out2) {
    constexpr int NJ = TN / 32;
    __shared__ bf16 sA[2][64 * 32];
    __shared__ bf16 sB[2][TN * 32];
    const int tid = threadIdx.x;
    const int lane = tid & 63, wave = tid >> 6;
    const int quad = lane >> 4, l16 = lane & 15;

    const int c = blockIdx.x & 7, sidx = blockIdx.x >> 3;
    const int xb = sidx % GX, tile = (sidx / GX) * 8 + c;
    const int mt = (MODE == 4) ? (tile >> 1) : tile;
    const int zz = (MODE == 4) ? (tile & 1) : 0;
    const int m0 = mt * 64, n0 = xb * TN;
    const int wm = (wave >> 1) * 32, wn = (wave & 1) * (TN / 2);

    const f32x4 zero = {0.f, 0.f, 0.f, 0.f};
    f32x4 acc[2][NJ];
#pragma unroll
    for (int i = 0; i < 2; ++i)
#pragma unroll
        for (int j = 0; j < NJ; ++j) acc[i][j] = zero;

    const int ar0 = m0 + (tid >> 2), ak0 = (tid & 3) * 8;
    const int br0 = n0 + (tid >> 2), br1 = n0 + ((tid + 256) >> 2);

    const int kb = (MODE == 4) ? zz * (K >> 1) : 0;
    const int ke = (MODE == 4) ? kb + (K >> 1) : K;

    auto stage = [&](int k0, int b) {
        gl_lds16(A + (size_t)ar0 * K + k0 + ak0, &sA[b][tid * 8]);
        gl_lds16(BT + (size_t)br0 * K + k0 + ak0, &sB[b][tid * 8]);
        if constexpr (TN == 128) {
            gl_lds16(BT + (size_t)br1 * K + k0 + ak0, &sB[b][(tid + 256) * 8]);
        } else if constexpr (TN == 96) {
            if (tid < 128)  // wave-uniform (2 waves)
                gl_lds16(BT + (size_t)br1 * K + k0 + ak0, &sB[b][(tid + 256) * 8]);
        }
    };
    auto compute = [&](int b) {
        bf16x8 af[2], bfr[NJ];
#pragma unroll
        for (int i = 0; i < 2; ++i)
            af[i] = *(const bf16x8*)&sA[b][(wm + i * 16 + l16) * 32 + quad * 8];
#pragma unroll
        for (int j = 0; j < NJ; ++j)
            bfr[j] = *(const bf16x8*)&sB[b][(wn + j * 16 + l16) * 32 + quad * 8];
#pragma unroll
        for (int i = 0; i < 2; ++i)
#pragma unroll
            for (int j = 0; j < NJ; ++j)
                acc[i][j] = mfma16(af[i], bfr[j], acc[i][j]);
    };

    stage(kb, 0);
    // step count even for all uses (24/24/12/48)
    for (int k0 = kb; k0 < ke; k0 += 64) {
        __syncthreads();
        if (k0 + 32 < ke) stage(k0 + 32, 1);
        compute(0);
        __syncthreads();
        if (k0 + 64 < ke) stage(k0 + 64, 0);
        compute(1);
    }

#pragma unroll
    for (int i = 0; i < 2; ++i) {
#pragma unroll
        for (int j = 0; j < NJ; ++j) {
            const int col = n0 + wn + j * 16 + l16;
#pragma unroll
            for (int r = 0; r < 4; ++r) {
                const int row = m0 + wm + i * 16 + quad * 4 + r;
                float v = acc[i][j][r];
                if (MODE == 0) {
                    int mat = col / 768;
                    int cc2 = col - mat * 768;
                    v += (mat == 0 ? bias0 : mat == 1 ? bias1 : bias2)[cc2];
                    if (mat == 0) v *= 0.18033688f;  // 0.125*log2(e) folded into q
                    int h = cc2 >> 6, d = cc2 & 63;
                    int b = row >> 11, sdx = row & 2047;
                    bf16* dst = (bf16*)(mat == 0 ? out0 : mat == 1 ? out1 : out2);
                    dst[((((size_t)b * 12 + h) * 2048 + sdx) << 6) + d] = (bf16)v;
                } else if (MODE == 2) {
                    v += bias0[col];
                    ((bf16*)out0)[(size_t)row * 3072 + col] = (bf16)fmaxf(v, 0.f);
                } else {  // MODE 4: bf16 partial
                    bf16* o = (bf16*)out0 + (size_t)zz * 4096 * N;
                    o[(size_t)row * N + col] = (bf16)v;
                }
            }
        }
    }
}

// ---------------- flash attention: V from global regs, kv-split 4 ----------------
// grid (qb=16, quarter=4, bh=24). Block: 128 q (4 waves x 32 q), 8 kv tiles of 64.
// LDS = qps 18KB + ks dbuf 16KB = 34.4KB -> 4 blocks/CU. lb(256,4) caps VGPR 128.
__global__ void __launch_bounds__(256, 4)
attn_kernel(const bf16* __restrict__ Q, const bf16* __restrict__ Kg,
            const bf16* __restrict__ VT, bf16* __restrict__ OP,
            float* __restrict__ LP) {
    const int S = 2048;
    __shared__ bf16 qps[9216];   // Q [128][64] swizzled, then ps 4x[32][72]
    __shared__ bf16 ks[2][4096];

    const int tid = threadIdx.x;
    const int lane = tid & 63, wave = tid >> 6;
    const int quad = lane >> 4, l16 = lane & 15;
    const int quarter = blockIdx.y, bh = blockIdx.z;
    const int q0 = blockIdx.x * 128;
    const bf16* Qb = Q + (size_t)bh * S * 64;
    const bf16* Kb = Kg + (size_t)bh * S * 64;
    const bf16* VTb = VT + (size_t)bh * 64 * S;

    const int kv_lo = quarter * (S / 4);

    auto stage = [&](int kv0, int b) {
#pragma unroll
        for (int cc = 0; cc < 2; ++cc) {
            int c = tid + cc * 256;
            int r = c >> 3, dg = (c & 7) ^ (r & 7);
            gl_lds16(Kb + (size_t)(kv0 + r) * 64 + dg * 8, &ks[b][c * 8]);
        }
    };

#pragma unroll
    for (int cc = 0; cc < 4; ++cc) {
        int c = tid + cc * 256;
        int r = c >> 3, dg = (c & 7) ^ (r & 7);
        gl_lds16(Qb + (size_t)(q0 + r) * 64 + dg * 8, &qps[c * 8]);
    }
    stage(kv_lo, 0);
    __syncthreads();

    bf16x8 qf[2][2];
#pragma unroll
    for (int jq = 0; jq < 2; ++jq) {
        int qr = wave * 32 + jq * 16 + l16;
#pragma unroll
        for (int kh = 0; kh < 2; ++kh)
            qf[jq][kh] = *(const bf16x8*)&qps[qr * 64 + (((kh * 4 + quad) ^ (l16 & 7)) * 8)];
    }

    bf16x8 ones;
#pragma unroll
    for (int i = 0; i < 8; ++i) ones[i] = (bf16)1.0f;

    f32x4 oacc[4][2];
    f32x4 lacc[2];
#pragma unroll
    for (int fd = 0; fd < 4; ++fd)
#pragma unroll
        for (int jq = 0; jq < 2; ++jq) oacc[fd][jq] = {0.f, 0.f, 0.f, 0.f};
    lacc[0] = {0.f, 0.f, 0.f, 0.f};
    lacc[1] = {0.f, 0.f, 0.f, 0.f};

    bf16* ps = &qps[wave * 2304];
    // V^T A-frag base: row = fd*16+l16, col = kv0 + kh*32 + quad*8 (16B/lane)
    const bf16* vbase = VTb + (size_t)l16 * S + quad * 8;

    auto compute = [&](int b, const bf16x8 vf[2][4]) {
        f32x4 sacc[4][2];
#pragma unroll
        for (int i = 0; i < 4; ++i)
#pragma unroll
            for (int jq = 0; jq < 2; ++jq) sacc[i][jq] = {0.f, 0.f, 0.f, 0.f};
#pragma unroll
        for (int kh = 0; kh < 2; ++kh) {
#pragma unroll
            for (int i = 0; i < 4; ++i) {
                int kr = i * 16 + l16;
                bf16x8 kf = *(const bf16x8*)&ks[b][kr * 64 + (((kh * 4 + quad) ^ (l16 & 7)) * 8)];
                sacc[i][0] = mfma16(kf, qf[0][kh], sacc[i][0]);
                sacc[i][1] = mfma16(kf, qf[1][kh], sacc[i][1]);
            }
        }
#pragma unroll
        for (int jq = 0; jq < 2; ++jq) {
            const int qr = jq * 16 + l16;
#pragma unroll
            for (int i = 0; i < 4; ++i) {
                bf16x4 pk;
#pragma unroll
                for (int r = 0; r < 4; ++r)
                    pk[r] = (bf16)__builtin_amdgcn_exp2f(sacc[i][jq][r]);
                *(bf16x4*)&ps[qr * 72 + i * 16 + quad * 4] = pk;
            }
        }
#pragma unroll
        for (int kh = 0; kh < 2; ++kh) {
            bf16x8 pb0 = *(const bf16x8*)&ps[(0 * 16 + l16) * 72 + kh * 32 + quad * 8];
            bf16x8 pb1 = *(const bf16x8*)&ps[(1 * 16 + l16) * 72 + kh * 32 + quad * 8];
            lacc[0] = mfma16(ones, pb0, lacc[0]);
            lacc[1] = mfma16(ones, pb1, lacc[1]);
#pragma unroll
            for (int fd = 0; fd < 4; ++fd) {
                oacc[fd][0] = mfma16(vf[kh][fd], pb0, oacc[fd][0]);
                oacc[fd][1] = mfma16(vf[kh][fd], pb1, oacc[fd][1]);
            }
        }
    };
    auto loadV = [&](int kv0, bf16x8 vf[2][4]) {
#pragma unroll
        for (int kh = 0; kh < 2; ++kh)
#pragma unroll
            for (int fd = 0; fd < 4; ++fd)
                vf[kh][fd] = *(const bf16x8*)(vbase + (size_t)(fd * 16) * S + kv0 + kh * 32);
    };

    for (int tt = 0; tt < 4; ++tt) {
        const int t0 = tt * 2;
        bf16x8 vf[2][4];
        __syncthreads();
        loadV(kv_lo + t0 * 64, vf);
        if (t0 + 1 < 8) stage(kv_lo + (t0 + 1) * 64, 1);
        compute(0, vf);
        __syncthreads();
        loadV(kv_lo + (t0 + 1) * 64, vf);
        if (t0 + 2 < 8) stage(kv_lo + (t0 + 2) * 64, 0);
        compute(1, vf);
    }

    const size_t rbase = (size_t)quarter * 24 * S + (size_t)bh * S + q0;
    if (quad == 0) {
#pragma unroll
        for (int jq = 0; jq < 2; ++jq)
            LP[rbase + wave * 32 + jq * 16 + l16] = lacc[jq][0];
    }
    bf16* op = OP + rbase * 64;
#pragma unroll
    for (int jq = 0; jq < 2; ++jq) {
        const int qr = wave * 32 + jq * 16 + l16;
#pragma unroll
        for (int fd = 0; fd < 4; ++fd) {
            bf16x4 ov;
#pragma unroll
            for (int r = 0; r < 4; ++r) ov[r] = (bf16)oacc[fd][jq][r];
            *(bf16x4*)&op[(size_t)qr * 64 + fd * 16 + quad * 4] = ov;
        }
    }
}

// ctx = sum(O_i)/sum(l_i), 4 partials, bf16
__global__ void __launch_bounds__(256)
attn_combine(const bf16* __restrict__ OP, const float* __restrict__ LP,
             bf16* __restrict__ CTX) {
    const int tid = threadIdx.x;
    const size_t r = (size_t)blockIdx.x * 32 + (tid >> 3);
    const int d0 = (tid & 7) * 8;
    const size_t RT = (size_t)24 * 2048;
    float l = LP[r] + LP[RT + r] + LP[2 * RT + r] + LP[3 * RT + r];
    float rinv = 1.f / l;
    float o[8] = {0, 0, 0, 0, 0, 0, 0, 0};
#pragma unroll
    for (int q = 0; q < 4; ++q) {
        bf16x8 a = *(const bf16x8*)(OP + (q * RT + r) * 64 + d0);
#pragma unroll
        for (int i = 0; i < 8; ++i) o[i] += (float)a[i];
    }
    int bh = (int)(r >> 11), s = (int)(r & 2047);
    int bb = bh / 12, h = bh - bb * 12;
    bf16x8 out;
#pragma unroll
    for (int i = 0; i < 8; ++i) out[i] = (bf16)(o[i] * rinv);
    *(bf16x8*)&CTX[(size_t)(bb * 2048 + s) * 768 + h * 64 + d0] = out;
}

// ---------------- host launch ----------------
extern "C" void kernel_launch(void* const* d_in, const int* in_sizes, int n_in,
                              void* d_out, int out_size, void* d_ws, size_t ws_size,
                              hipStream_t stream) {
    const int S = 2048, D = 768, F = 3072, M = 4096;
    const float* x = (const float*)d_in[0];
    const float* wq = (const float*)d_in[2];
    const float* bq = (const float*)d_in[3];
    const float* wk = (const float*)d_in[4];
    const float* bk = (const float*)d_in[5];
    const float* wv = (const float*)d_in[6];
    const float* bv = (const float*)d_in[7];
    const float* wo = (const float*)d_in[8];
    const float* bo = (const float*)d_in[9];
    const float* w1 = (const float*)d_in[10];
    const float* b1 = (const float*)d_in[11];
    const float* w2 = (const float*)d_in[12];
    const float* b2 = (const float*)d_in[13];
    const float* alpha1 = (const float*)d_in[14];
    const float* beta1 = (const float*)d_in[15];
    const float* alpha2 = (const float*)d_in[16];
    const float* beta2 = (const float*)d_in[17];

    char* p = (char*)d_ws;
    auto take = [&](size_t n) { char* r = p; p += (n + 255) & ~(size_t)255; return r; };
    bf16* wqkvT = (bf16*)take((size_t)3 * D * D * 2);
    bf16* woT   = (bf16*)take((size_t)D * D * 2);
    bf16* w1T   = (bf16*)take((size_t)F * D * 2);
    bf16* w2T   = (bf16*)take((size_t)D * F * 2);
    bf16* xn    = (bf16*)take((size_t)M * D * 2);
    float* x2   = (float*)take((size_t)M * D * 4);
    bf16* qb    = (bf16*)take((size_t)M * D * 2);
    bf16* kb    = (bf16*)take((size_t)M * D * 2);
    bf16* vb    = (bf16*)take((size_t)M * D * 2);
    bf16* ctx   = (bf16*)take((size_t)M * D * 2);
    bf16* hb    = qb;  // FFN1 out aliases q/k (dead after attention)
    bf16* VT    = (bf16*)take((size_t)M * D * 2);
    bf16* op    = (bf16*)take((size_t)4 * M * D * 2);   // attn O partials (bf16, 4-way)
    float* lp   = (float*)take((size_t)4 * 24 * S * 4);
    bf16* pp    = (bf16*)take((size_t)2 * M * D * 2);   // split-K bf16 partials

    transpose_all<<<dim3(6912), 256, 0, stream>>>(wq, wk, wv, wo, w1, w2,
                                                  wqkvT, woT, w1T, w2T);
    ln_kernel<<<M, 256, 0, stream>>>(x, xn, alpha1, beta1);
    // QKV: TM=64 TN=96, tiles=64, GX=24 -> 1536 blocks (6/CU)
    gemm_kernel<0, 96, 24><<<dim3(1536), 256, 0, stream>>>(
        xn, wqkvT, D, 3 * D, bq, bk, bv, qb, kb, vb);
    vtrans_kernel<<<dim3(S / 64, 24), 256, 0, stream>>>(vb, VT);
    // attention: kv-split 4, grid 1536, 4 blocks/CU
    attn_kernel<<<dim3(S / 128, 4, 24), 256, 0, stream>>>(qb, kb, VT, op, lp);
    attn_combine<<<dim3(24 * S / 32), 256, 0, stream>>>(op, lp, ctx);
    // OPROJ split-K=2: TM=64 TN=64, tiles=128, GX=12 -> 1536 blocks
    gemm_kernel<4, 64, 12><<<dim3(1536), 256, 0, stream>>>(
        ctx, woT, D, D, nullptr, nullptr, nullptr, pp, nullptr, nullptr);
    combine_ln2<<<M, 256, 0, stream>>>(pp, bo, x, x2, xn, alpha2, beta2);
    // FFN1: TM=64 TN=128, tiles=64, GX=24 -> 1536 blocks
    gemm_kernel<2, 128, 24><<<dim3(1536), 256, 0, stream>>>(
        xn, w1T, D, F, b1, nullptr, nullptr, hb, nullptr, nullptr);
    // FFN2 split-K=2: TM=64 TN=96, tiles=128, GX=8 -> 1024 blocks
    gemm_kernel<4, 96, 8><<<dim3(1024), 256, 0, stream>>>(
        hb, w2T, F, D, nullptr, nullptr, nullptr, pp, nullptr, nullptr);
    ffn2_combine<<<dim3(M * D / 1024), 256, 0, stream>>>(pp, b2, x2, (float*)d_out);
}

// Round 9
// 283.678 us; speedup vs baseline: 1.2573x; 1.2573x over previous
//
#include <hip/hip_runtime.h>
#include <cstdint>

// EncoderBlock: pre-LN transformer block. B=2,S=2048,D=768,F=3072,H=12,dk=64.
// bf16 MFMA 16x16x32; fp32 accumulate.
// R9: revert R8 (TM=64 GEMMs + V-from-global attn both regressed: raw-gather
//     latency replaced LDS staging, write amplification at kv4). Back to R7
//     structure; QKV epilogue now writes V^T directly (packed bf16x4 along s),
//     vtrans kernel deleted.

typedef __bf16 bf16;
typedef __bf16 bf16x4 __attribute__((ext_vector_type(4)));
typedef __bf16 bf16x8 __attribute__((ext_vector_type(8)));
typedef float f32x4 __attribute__((ext_vector_type(4)));

#define DEV __device__ __forceinline__

DEV f32x4 mfma16(bf16x8 a, bf16x8 b, f32x4 c) {
    return __builtin_amdgcn_mfma_f32_16x16x32_bf16(a, b, c, 0, 0, 0);
}

typedef unsigned int u32;
typedef const u32 __attribute__((address_space(1))) gu32;
typedef u32 __attribute__((address_space(3))) lu32;

DEV void gl_lds16(const void* g, void* l) {
    __builtin_amdgcn_global_load_lds((gu32*)(uintptr_t)g,
                                     (lu32*)(u32)(uintptr_t)l, 16, 0, 0);
}

// ---------------- all weight transposes (fp32->bf16, [K][N]->[N][K]) ----------------
__global__ void __launch_bounds__(256)
transpose_all(const float* __restrict__ wq, const float* __restrict__ wk,
              const float* __restrict__ wv, const float* __restrict__ wo,
              const float* __restrict__ w1, const float* __restrict__ w2,
              bf16* __restrict__ qkvT, bf16* __restrict__ woT,
              bf16* __restrict__ w1T, bf16* __restrict__ w2T) {
    __shared__ float t[32][33];
    int id = blockIdx.x;
    const float* in;
    bf16* out;
    int K, N, bx, by;
    if (id < 2304) {
        int mat = id / 576, r = id - mat * 576;
        K = 768; N = 768; bx = r % 24; by = r / 24;
        in = mat == 0 ? wq : mat == 1 ? wk : mat == 2 ? wv : wo;
        out = mat == 3 ? woT : qkvT + (size_t)mat * 768 * 768;
    } else if (id < 4608) {
        int r = id - 2304;
        K = 768; N = 3072; bx = r % 96; by = r / 96;
        in = w1; out = w1T;
    } else {
        int r = id - 4608;
        K = 3072; N = 768; bx = r % 24; by = r / 24;
        in = w2; out = w2T;
    }
    const int tx = threadIdx.x & 31, ty = threadIdx.x >> 5;
    const int n0 = bx * 32, k0 = by * 32;
#pragma unroll
    for (int i = 0; i < 32; i += 8)
        t[ty + i][tx] = in[(size_t)(k0 + ty + i) * N + n0 + tx];
    __syncthreads();
#pragma unroll
    for (int i = 0; i < 32; i += 8)
        out[(size_t)(n0 + ty + i) * K + k0 + tx] = (bf16)t[tx][ty + i];
}

// ---------------- layernorm (ddof=1) ----------------
__global__ void __launch_bounds__(256)
ln_kernel(const float* __restrict__ X, bf16* __restrict__ Y,
          const float* __restrict__ alpha, const float* __restrict__ beta) {
    __shared__ float red[8];
    const int row = blockIdx.x;
    const int tid = threadIdx.x;
    const float* xr = X + (size_t)row * 768;
    float x0 = xr[tid], x1 = xr[tid + 256], x2 = xr[tid + 512];
    float s = x0 + x1 + x2, sq = x0 * x0 + x1 * x1 + x2 * x2;
#pragma unroll
    for (int off = 32; off >= 1; off >>= 1) {
        s += __shfl_xor(s, off, 64);
        sq += __shfl_xor(sq, off, 64);
    }
    const int wave = tid >> 6;
    if ((tid & 63) == 0) { red[wave] = s; red[4 + wave] = sq; }
    __syncthreads();
    s = red[0] + red[1] + red[2] + red[3];
    sq = red[4] + red[5] + red[6] + red[7];
    float mean = s * (1.f / 768.f);
    float var = (sq - 768.f * mean * mean) * (1.f / 767.f);
    float a = alpha[0] * rsqrtf(var + 1e-6f), bb = beta[0];
    bf16* yr = Y + (size_t)row * 768;
    yr[tid]       = (bf16)((x0 - mean) * a + bb);
    yr[tid + 256] = (bf16)((x1 - mean) * a + bb);
    yr[tid + 512] = (bf16)((x2 - mean) * a + bb);
}

// combine OPROJ split-K bf16 partials + bias + residual, then LN2
__global__ void __launch_bounds__(256)
combine_ln2(const bf16* __restrict__ P, const float* __restrict__ bo,
            const float* __restrict__ X, float* __restrict__ X2,
            bf16* __restrict__ XN,
            const float* __restrict__ alpha, const float* __restrict__ beta) {
    __shared__ float red[8];
    const int row = blockIdx.x;
    const int tid = threadIdx.x;
    const size_t base = (size_t)row * 768;
    const bf16* p0 = P + base;
    const bf16* p1 = P + (size_t)4096 * 768 + base;
    float v[3];
#pragma unroll
    for (int i = 0; i < 3; ++i) {
        int c = tid + i * 256;
        v[i] = (float)p0[c] + (float)p1[c] + bo[c] + X[base + c];
        X2[base + c] = v[i];
    }
    float s = v[0] + v[1] + v[2];
    float sq = v[0] * v[0] + v[1] * v[1] + v[2] * v[2];
#pragma unroll
    for (int off = 32; off >= 1; off >>= 1) {
        s += __shfl_xor(s, off, 64);
        sq += __shfl_xor(sq, off, 64);
    }
    const int wave = tid >> 6;
    if ((tid & 63) == 0) { red[wave] = s; red[4 + wave] = sq; }
    __syncthreads();
    s = red[0] + red[1] + red[2] + red[3];
    sq = red[4] + red[5] + red[6] + red[7];
    float mean = s * (1.f / 768.f);
    float var = (sq - 768.f * mean * mean) * (1.f / 767.f);
    float a = alpha[0] * rsqrtf(var + 1e-6f), bb = beta[0];
#pragma unroll
    for (int i = 0; i < 3; ++i)
        XN[base + tid + i * 256] = (bf16)((v[i] - mean) * a + bb);
}

__global__ void __launch_bounds__(256)
ffn2_combine(const bf16* __restrict__ P, const float* __restrict__ b2,
             const float* __restrict__ X2, float* __restrict__ OUT) {
    const size_t i4 = (size_t)blockIdx.x * 256 + threadIdx.x;
    const size_t f = i4 * 4;
    const int col = (int)(f % 768);
    bf16x4 a = *(const bf16x4*)(P + f);
    bf16x4 b = *(const bf16x4*)(P + (size_t)4096 * 768 + f);
    f32x4 x = *(const f32x4*)(X2 + f);
    f32x4 bi = *(const f32x4*)(b2 + col);
    f32x4 o;
#pragma unroll
    for (int i = 0; i < 4; ++i) o[i] = (float)a[i] + (float)b[i] + x[i] + bi[i];
    *(f32x4*)(OUT + f) = o;
}

// ---------------- GEMM: TM=128, prefetch dbuf, XCD-aware swizzle ----------------
// Flat grid = GX * Tiles. c=blockIdx&7 (XCD), s=blockIdx>>3: xb=s%GX, tile=(s/GX)*8+c.
// MODE 0: QKV -> q/k scatter bf16 [B,H,S,64]; V written TRANSPOSED [bh][64][2048]
//         (+biases; q pre-scaled by 0.125*log2e)
// MODE 2: FFN1 -> bf16 relu(acc + b1)
// MODE 4: split-K partial -> bf16 out0[z][row][col] (mt=tile>>1, zz=tile&1)
template <int MODE, int TN, int GX>
__global__ void __launch_bounds__(256)
gemm_kernel(const bf16* __restrict__ A, const bf16* __restrict__ BT,
            int K, int N,
            const float* __restrict__ bias0, const float* __restrict__ bias1,
            const float* __restrict__ bias2,
            void* __restrict__ out0, void* __restrict__ out1, void* __restrict__ out2) {
    constexpr int NJ = TN / 32;
    __shared__ bf16 sA[2][128 * 32];
    __shared__ bf16 sB[2][TN * 32];
    const int tid = threadIdx.x;
    const int lane = tid & 63, wave = tid >> 6;
    const int quad = lane >> 4, l16 = lane & 15;

    const int c = blockIdx.x & 7, sidx = blockIdx.x >> 3;
    const int xb = sidx % GX, tile = (sidx / GX) * 8 + c;
    const int mt = (MODE == 4) ? (tile >> 1) : tile;
    const int zz = (MODE == 4) ? (tile & 1) : 0;
    const int m0 = mt * 128, n0 = xb * TN;
    const int wm = (wave >> 1) * 64, wn = (wave & 1) * (TN / 2);

    const f32x4 zero = {0.f, 0.f, 0.f, 0.f};
    f32x4 acc[4][NJ];
#pragma unroll
    for (int i = 0; i < 4; ++i)
#pragma unroll
        for (int j = 0; j < NJ; ++j) acc[i][j] = zero;

    const int c0 = tid, c1 = tid + 256;
    const int ar0 = m0 + (c0 >> 2), ak0 = (c0 & 3) * 8;
    const int ar1 = m0 + (c1 >> 2), ak1 = (c1 & 3) * 8;
    const int br0 = n0 + (c0 >> 2), br1 = n0 + (c1 >> 2);

    const int kb = (MODE == 4) ? zz * (K >> 1) : 0;
    const int ke = (MODE == 4) ? kb + (K >> 1) : K;

    auto stage = [&](int k0, int b) {
        gl_lds16(A + (size_t)ar0 * K + k0 + ak0, &sA[b][c0 * 8]);
        gl_lds16(A + (size_t)ar1 * K + k0 + ak1, &sA[b][c1 * 8]);
        gl_lds16(BT + (size_t)br0 * K + k0 + ak0, &sB[b][c0 * 8]);
        if constexpr (TN * 4 > 256) {
            if (tid < TN * 4 - 256)  // wave-uniform (multiple of 64)
                gl_lds16(BT + (size_t)br1 * K + k0 + ak1, &sB[b][c1 * 8]);
        }
    };
    auto compute = [&](int b) {
        bf16x8 af[4], bfr[NJ];
#pragma unroll
        for (int i = 0; i < 4; ++i)
            af[i] = *(const bf16x8*)&sA[b][(wm + i * 16 + l16) * 32 + quad * 8];
#pragma unroll
        for (int j = 0; j < NJ; ++j)
            bfr[j] = *(const bf16x8*)&sB[b][(wn + j * 16 + l16) * 32 + quad * 8];
#pragma unroll
        for (int i = 0; i < 4; ++i)
#pragma unroll
            for (int j = 0; j < NJ; ++j)
                acc[i][j] = mfma16(af[i], bfr[j], acc[i][j]);
    };

    stage(kb, 0);
    for (int k0 = kb; k0 < ke; k0 += 64) {
        __syncthreads();
        if (k0 + 32 < ke) stage(k0 + 32, 1);
        compute(0);
        __syncthreads();
        if (k0 + 64 < ke) stage(k0 + 64, 0);
        compute(1);
    }

#pragma unroll
    for (int i = 0; i < 4; ++i) {
#pragma unroll
        for (int j = 0; j < NJ; ++j) {
            const int col = n0 + wn + j * 16 + l16;
            if (MODE == 0) {
                int mat = col / 768;
                int cc2 = col - mat * 768;
                float bias = (mat == 0 ? bias0 : mat == 1 ? bias1 : bias2)[cc2];
                int h = cc2 >> 6, d = cc2 & 63;
                if (mat == 2) {
                    // V^T store: rows r are s-consecutive -> packed bf16x4
                    int row0 = m0 + wm + i * 16 + quad * 4;
                    int b = row0 >> 11, s0 = row0 & 2047;
                    bf16x4 pv;
#pragma unroll
                    for (int r = 0; r < 4; ++r) pv[r] = (bf16)(acc[i][j][r] + bias);
                    *(bf16x4*)&((bf16*)out2)[(((size_t)b * 12 + h) * 64 + d) * 2048 + s0] = pv;
                } else {
#pragma unroll
                    for (int r = 0; r < 4; ++r) {
                        const int row = m0 + wm + i * 16 + quad * 4 + r;
                        float v = acc[i][j][r] + bias;
                        if (mat == 0) v *= 0.18033688f;  // 0.125*log2(e) folded into q
                        int b = row >> 11, sdx = row & 2047;
                        bf16* dst = (bf16*)(mat == 0 ? out0 : out1);
                        dst[((((size_t)b * 12 + h) * 2048 + sdx) << 6) + d] = (bf16)v;
                    }
                }
            } else {
#pragma unroll
                for (int r = 0; r < 4; ++r) {
                    const int row = m0 + wm + i * 16 + quad * 4 + r;
                    float v = acc[i][j][r];
                    if (MODE == 2) {
                        v += bias0[col];
                        ((bf16*)out0)[(size_t)row * 3072 + col] = (bf16)fmaxf(v, 0.f);
                    } else {  // MODE 4: bf16 partial
                        bf16* o = (bf16*)out0 + (size_t)zz * 4096 * N;
                        o[(size_t)row * N + col] = (bf16)v;
                    }
                }
            }
        }
    }
}

// ---------------- flash attention (R7-proven: S^T dataflow, LDS dbuf, kv-split 2) ----------------
__global__ void __launch_bounds__(256)
attn_kernel(const bf16* __restrict__ Q, const bf16* __restrict__ Kg,
            const bf16* __restrict__ VT, bf16* __restrict__ OP,
            float* __restrict__ LP) {
    const int S = 2048;
    __shared__ bf16 qps[9216];
    __shared__ bf16 ks[2][4096];
    __shared__ bf16 vts[2][4096];

    const int tid = threadIdx.x;
    const int lane = tid & 63, wave = tid >> 6;
    const int quad = lane >> 4, l16 = lane & 15;
    const int half = blockIdx.y, bh = blockIdx.z;
    const int q0 = blockIdx.x * 128;
    const bf16* Qb = Q + (size_t)bh * S * 64;
    const bf16* Kb = Kg + (size_t)bh * S * 64;
    const bf16* VTb = VT + (size_t)bh * 64 * S;

    const int kv_lo = half * (S / 2);

    auto stage = [&](int kv0, int b) {
#pragma unroll
        for (int cc = 0; cc < 2; ++cc) {
            int c = tid + cc * 256;
            int r = c >> 3, dg = (c & 7) ^ (r & 7);
            gl_lds16(Kb + (size_t)(kv0 + r) * 64 + dg * 8, &ks[b][c * 8]);
            gl_lds16(VTb + (size_t)r * S + kv0 + dg * 8, &vts[b][c * 8]);
        }
    };

#pragma unroll
    for (int cc = 0; cc < 4; ++cc) {
        int c = tid + cc * 256;
        int r = c >> 3, dg = (c & 7) ^ (r & 7);
        gl_lds16(Qb + (size_t)(q0 + r) * 64 + dg * 8, &qps[c * 8]);
    }
    stage(kv_lo, 0);
    __syncthreads();

    bf16x8 qf[2][2];
#pragma unroll
    for (int jq = 0; jq < 2; ++jq) {
        int qr = wave * 32 + jq * 16 + l16;
#pragma unroll
        for (int kh = 0; kh < 2; ++kh)
            qf[jq][kh] = *(const bf16x8*)&qps[qr * 64 + (((kh * 4 + quad) ^ (l16 & 7)) * 8)];
    }

    bf16x8 ones;
#pragma unroll
    for (int i = 0; i < 8; ++i) ones[i] = (bf16)1.0f;

    f32x4 oacc[4][2];
    f32x4 lacc[2];
#pragma unroll
    for (int fd = 0; fd < 4; ++fd)
#pragma unroll
        for (int jq = 0; jq < 2; ++jq) oacc[fd][jq] = {0.f, 0.f, 0.f, 0.f};
    lacc[0] = {0.f, 0.f, 0.f, 0.f};
    lacc[1] = {0.f, 0.f, 0.f, 0.f};

    bf16* ps = &qps[wave * 2304];

    auto compute = [&](int b) {
        f32x4 sacc[4][2];
#pragma unroll
        for (int i = 0; i < 4; ++i)
#pragma unroll
            for (int jq = 0; jq < 2; ++jq) sacc[i][jq] = {0.f, 0.f, 0.f, 0.f};
#pragma unroll
        for (int kh = 0; kh < 2; ++kh) {
#pragma unroll
            for (int i = 0; i < 4; ++i) {
                int kr = i * 16 + l16;
                bf16x8 kf = *(const bf16x8*)&ks[b][kr * 64 + (((kh * 4 + quad) ^ (l16 & 7)) * 8)];
                sacc[i][0] = mfma16(kf, qf[0][kh], sacc[i][0]);
                sacc[i][1] = mfma16(kf, qf[1][kh], sacc[i][1]);
            }
        }
#pragma unroll
        for (int jq = 0; jq < 2; ++jq) {
            const int qr = jq * 16 + l16;
#pragma unroll
            for (int i = 0; i < 4; ++i) {
                bf16x4 pk;
#pragma unroll
                for (int r = 0; r < 4; ++r)
                    pk[r] = (bf16)__builtin_amdgcn_exp2f(sacc[i][jq][r]);
                *(bf16x4*)&ps[qr * 72 + i * 16 + quad * 4] = pk;
            }
        }
#pragma unroll
        for (int kh = 0; kh < 2; ++kh) {
            bf16x8 pb0 = *(const bf16x8*)&ps[(0 * 16 + l16) * 72 + kh * 32 + quad * 8];
            bf16x8 pb1 = *(const bf16x8*)&ps[(1 * 16 + l16) * 72 + kh * 32 + quad * 8];
            lacc[0] = mfma16(ones, pb0, lacc[0]);
            lacc[1] = mfma16(ones, pb1, lacc[1]);
#pragma unroll
            for (int fd = 0; fd < 4; ++fd) {
                int dr = fd * 16 + l16;
                bf16x8 vf = *(const bf16x8*)&vts[b][dr * 64 + (((kh * 4 + quad) ^ (l16 & 7)) * 8)];
                oacc[fd][0] = mfma16(vf, pb0, oacc[fd][0]);
                oacc[fd][1] = mfma16(vf, pb1, oacc[fd][1]);
            }
        }
    };

    for (int tt = 0; tt < 8; ++tt) {
        const int t0 = tt * 2;
        __syncthreads();
        if (t0 + 1 < 16) stage(kv_lo + (t0 + 1) * 64, 1);
        compute(0);
        __syncthreads();
        if (t0 + 2 < 16) stage(kv_lo + (t0 + 2) * 64, 0);
        compute(1);
    }

    const size_t rbase = (size_t)half * 24 * S + (size_t)bh * S + q0;
    if (quad == 0) {
#pragma unroll
        for (int jq = 0; jq < 2; ++jq)
            LP[rbase + wave * 32 + jq * 16 + l16] = lacc[jq][0];
    }
    bf16* op = OP + rbase * 64;
#pragma unroll
    for (int jq = 0; jq < 2; ++jq) {
        const int qr = wave * 32 + jq * 16 + l16;
#pragma unroll
        for (int fd = 0; fd < 4; ++fd) {
            bf16x4 ov;
#pragma unroll
            for (int r = 0; r < 4; ++r) ov[r] = (bf16)oacc[fd][jq][r];
            *(bf16x4*)&op[(size_t)qr * 64 + fd * 16 + quad * 4] = ov;
        }
    }
}

// ctx = (O0+O1)/(l0+l1), bf16
__global__ void __launch_bounds__(256)
attn_combine(const bf16* __restrict__ OP, const float* __restrict__ LP,
             bf16* __restrict__ CTX) {
    const int tid = threadIdx.x;
    const size_t r = (size_t)blockIdx.x * 32 + (tid >> 3);
    const int d0 = (tid & 7) * 8;
    const size_t RT = (size_t)24 * 2048;
    float rinv = 1.f / (LP[r] + LP[RT + r]);
    bf16x8 a = *(const bf16x8*)(OP + r * 64 + d0);
    bf16x8 b = *(const bf16x8*)(OP + (RT + r) * 64 + d0);
    int bh = (int)(r >> 11), s = (int)(r & 2047);
    int bb = bh / 12, h = bh - bb * 12;
    bf16x8 out;
#pragma unroll
    for (int i = 0; i < 8; ++i) out[i] = (bf16)(((float)a[i] + (float)b[i]) * rinv);
    *(bf16x8*)&CTX[(size_t)(bb * 2048 + s) * 768 + h * 64 + d0] = out;
}

// ---------------- host launch ----------------
extern "C" void kernel_launch(void* const* d_in, const int* in_sizes, int n_in,
                              void* d_out, int out_size, void* d_ws, size_t ws_size,
                              hipStream_t stream) {
    const int S = 2048, D = 768, F = 3072, M = 4096;
    const float* x = (const float*)d_in[0];
    const float* wq = (const float*)d_in[2];
    const float* bq = (const float*)d_in[3];
    const float* wk = (const float*)d_in[4];
    const float* bk = (const float*)d_in[5];
    const float* wv = (const float*)d_in[6];
    const float* bv = (const float*)d_in[7];
    const float* wo = (const float*)d_in[8];
    const float* bo = (const float*)d_in[9];
    const float* w1 = (const float*)d_in[10];
    const float* b1 = (const float*)d_in[11];
    const float* w2 = (const float*)d_in[12];
    const float* b2 = (const float*)d_in[13];
    const float* alpha1 = (const float*)d_in[14];
    const float* beta1 = (const float*)d_in[15];
    const float* alpha2 = (const float*)d_in[16];
    const float* beta2 = (const float*)d_in[17];

    char* p = (char*)d_ws;
    auto take = [&](size_t n) { char* r = p; p += (n + 255) & ~(size_t)255; return r; };
    bf16* wqkvT = (bf16*)take((size_t)3 * D * D * 2);
    bf16* woT   = (bf16*)take((size_t)D * D * 2);
    bf16* w1T   = (bf16*)take((size_t)F * D * 2);
    bf16* w2T   = (bf16*)take((size_t)D * F * 2);
    bf16* xn    = (bf16*)take((size_t)M * D * 2);
    float* x2   = (float*)take((size_t)M * D * 4);
    bf16* qb    = (bf16*)take((size_t)M * D * 2);
    bf16* kb    = (bf16*)take((size_t)M * D * 2);
    bf16* ctx   = (bf16*)take((size_t)M * D * 2);
    bf16* hb    = qb;  // FFN1 out aliases q (dead after attention)
    bf16* VT    = (bf16*)take((size_t)M * D * 2);   // V^T written directly by QKV
    bf16* op    = (bf16*)take((size_t)2 * M * D * 2);
    float* lp   = (float*)take((size_t)2 * 24 * S * 4);
    bf16* pp    = (bf16*)take((size_t)2 * M * D * 2);

    transpose_all<<<dim3(6912), 256, 0, stream>>>(wq, wk, wv, wo, w1, w2,
                                                  wqkvT, woT, w1T, w2T);
    ln_kernel<<<M, 256, 0, stream>>>(x, xn, alpha1, beta1);
    // QKV: TM=128 TN=96, tiles=32, GX=24 -> 768 blocks; V written transposed
    gemm_kernel<0, 96, 24><<<dim3(768), 256, 0, stream>>>(
        xn, wqkvT, D, 3 * D, bq, bk, bv, qb, kb, VT);
    attn_kernel<<<dim3(S / 128, 2, 24), 256, 0, stream>>>(qb, kb, VT, op, lp);
    attn_combine<<<dim3(24 * S / 32), 256, 0, stream>>>(op, lp, ctx);
    // OPROJ split-K=2: TM=128 TN=64, tiles=64, GX=12 -> 768 blocks
    gemm_kernel<4, 64, 12><<<dim3(768), 256, 0, stream>>>(
        ctx, woT, D, D, nullptr, nullptr, nullptr, pp, nullptr, nullptr);
    combine_ln2<<<M, 256, 0, stream>>>(pp, bo, x, x2, xn, alpha2, beta2);
    // FFN1: TM=128 TN=128, tiles=32, GX=24 -> 768 blocks
    gemm_kernel<2, 128, 24><<<dim3(768), 256, 0, stream>>>(
        xn, w1T, D, F, b1, nullptr, nullptr, hb, nullptr, nullptr);
    // FFN2 split-K=2: TM=128 TN=64, tiles=64, GX=12 -> 768 blocks
    gemm_kernel<4, 64, 12><<<dim3(768), 256, 0, stream>>>(
        hb, w2T, F, D, nullptr, nullptr, nullptr, pp, nullptr, nullptr);
    ffn2_combine<<<dim3(M * D / 1024), 256, 0, stream>>>(pp, b2, x2, (float*)d_out);
}

// Round 10
// 273.013 us; speedup vs baseline: 1.3065x; 1.0391x over previous
//
#include <hip/hip_runtime.h>
#include <cstdint>

// EncoderBlock: pre-LN transformer block. B=2,S=2048,D=768,F=3072,H=12,dk=64.
// bf16 MFMA 16x16x32; fp32 accumulate.
// R10: BK=64 double-buffered split-K GEMM for OPROJ/FFN2 (barrier count halved;
//      XOR-chunk-swizzled LDS layout, 2-way-conflict-free); transpose_all+LN1
//      fused into one prep launch (11 -> 9 dispatches). Rest = R9.

typedef __bf16 bf16;
typedef __bf16 bf16x4 __attribute__((ext_vector_type(4)));
typedef __bf16 bf16x8 __attribute__((ext_vector_type(8)));
typedef float f32x4 __attribute__((ext_vector_type(4)));

#define DEV __device__ __forceinline__

DEV f32x4 mfma16(bf16x8 a, bf16x8 b, f32x4 c) {
    return __builtin_amdgcn_mfma_f32_16x16x32_bf16(a, b, c, 0, 0, 0);
}

typedef unsigned int u32;
typedef const u32 __attribute__((address_space(1))) gu32;
typedef u32 __attribute__((address_space(3))) lu32;

DEV void gl_lds16(const void* g, void* l) {
    __builtin_amdgcn_global_load_lds((gu32*)(uintptr_t)g,
                                     (lu32*)(u32)(uintptr_t)l, 16, 0, 0);
}

// ---------------- prep: weight transposes + LN1, one launch ----------------
// blocks 0..6911: transpose tiles (0..2303 = 4x 768x768; ..4607 = w1; ..6911 = w2)
// blocks 6912..11007: LN1 row (id-6912)
__global__ void __launch_bounds__(256)
prep_kernel(const float* __restrict__ wq, const float* __restrict__ wk,
            const float* __restrict__ wv, const float* __restrict__ wo,
            const float* __restrict__ w1, const float* __restrict__ w2,
            bf16* __restrict__ qkvT, bf16* __restrict__ woT,
            bf16* __restrict__ w1T, bf16* __restrict__ w2T,
            const float* __restrict__ X, bf16* __restrict__ XN,
            const float* __restrict__ alpha, const float* __restrict__ beta) {
    __shared__ float t[32][33];
    const int id = blockIdx.x;
    const int tid = threadIdx.x;
    if (id >= 6912) {
        // ---- LN1 (ddof=1) ----
        float* red = &t[0][0];
        const int row = id - 6912;
        const float* xr = X + (size_t)row * 768;
        float x0 = xr[tid], x1 = xr[tid + 256], x2 = xr[tid + 512];
        float s = x0 + x1 + x2, sq = x0 * x0 + x1 * x1 + x2 * x2;
#pragma unroll
        for (int off = 32; off >= 1; off >>= 1) {
            s += __shfl_xor(s, off, 64);
            sq += __shfl_xor(sq, off, 64);
        }
        const int wave = tid >> 6;
        if ((tid & 63) == 0) { red[wave] = s; red[4 + wave] = sq; }
        __syncthreads();
        s = red[0] + red[1] + red[2] + red[3];
        sq = red[4] + red[5] + red[6] + red[7];
        float mean = s * (1.f / 768.f);
        float var = (sq - 768.f * mean * mean) * (1.f / 767.f);
        float a = alpha[0] * rsqrtf(var + 1e-6f), bb = beta[0];
        bf16* yr = XN + (size_t)row * 768;
        yr[tid]       = (bf16)((x0 - mean) * a + bb);
        yr[tid + 256] = (bf16)((x1 - mean) * a + bb);
        yr[tid + 512] = (bf16)((x2 - mean) * a + bb);
        return;
    }
    // ---- weight transpose fp32->bf16, [K][N]->[N][K] ----
    const float* in;
    bf16* out;
    int K, N, bx, by;
    if (id < 2304) {
        int mat = id / 576, r = id - mat * 576;
        K = 768; N = 768; bx = r % 24; by = r / 24;
        in = mat == 0 ? wq : mat == 1 ? wk : mat == 2 ? wv : wo;
        out = mat == 3 ? woT : qkvT + (size_t)mat * 768 * 768;
    } else if (id < 4608) {
        int r = id - 2304;
        K = 768; N = 3072; bx = r % 96; by = r / 96;
        in = w1; out = w1T;
    } else {
        int r = id - 4608;
        K = 3072; N = 768; bx = r % 24; by = r / 24;
        in = w2; out = w2T;
    }
    const int tx = tid & 31, ty = tid >> 5;
    const int n0 = bx * 32, k0 = by * 32;
#pragma unroll
    for (int i = 0; i < 32; i += 8)
        t[ty + i][tx] = in[(size_t)(k0 + ty + i) * N + n0 + tx];
    __syncthreads();
#pragma unroll
    for (int i = 0; i < 32; i += 8)
        out[(size_t)(n0 + ty + i) * K + k0 + tx] = (bf16)t[tx][ty + i];
}

// combine OPROJ split-K bf16 partials + bias + residual, then LN2
__global__ void __launch_bounds__(256)
combine_ln2(const bf16* __restrict__ P, const float* __restrict__ bo,
            const float* __restrict__ X, float* __restrict__ X2,
            bf16* __restrict__ XN,
            const float* __restrict__ alpha, const float* __restrict__ beta) {
    __shared__ float red[8];
    const int row = blockIdx.x;
    const int tid = threadIdx.x;
    const size_t base = (size_t)row * 768;
    const bf16* p0 = P + base;
    const bf16* p1 = P + (size_t)4096 * 768 + base;
    float v[3];
#pragma unroll
    for (int i = 0; i < 3; ++i) {
        int c = tid + i * 256;
        v[i] = (float)p0[c] + (float)p1[c] + bo[c] + X[base + c];
        X2[base + c] = v[i];
    }
    float s = v[0] + v[1] + v[2];
    float sq = v[0] * v[0] + v[1] * v[1] + v[2] * v[2];
#pragma unroll
    for (int off = 32; off >= 1; off >>= 1) {
        s += __shfl_xor(s, off, 64);
        sq += __shfl_xor(sq, off, 64);
    }
    const int wave = tid >> 6;
    if ((tid & 63) == 0) { red[wave] = s; red[4 + wave] = sq; }
    __syncthreads();
    s = red[0] + red[1] + red[2] + red[3];
    sq = red[4] + red[5] + red[6] + red[7];
    float mean = s * (1.f / 768.f);
    float var = (sq - 768.f * mean * mean) * (1.f / 767.f);
    float a = alpha[0] * rsqrtf(var + 1e-6f), bb = beta[0];
#pragma unroll
    for (int i = 0; i < 3; ++i)
        XN[base + tid + i * 256] = (bf16)((v[i] - mean) * a + bb);
}

__global__ void __launch_bounds__(256)
ffn2_combine(const bf16* __restrict__ P, const float* __restrict__ b2,
             const float* __restrict__ X2, float* __restrict__ OUT) {
    const size_t i4 = (size_t)blockIdx.x * 256 + threadIdx.x;
    const size_t f = i4 * 4;
    const int col = (int)(f % 768);
    bf16x4 a = *(const bf16x4*)(P + f);
    bf16x4 b = *(const bf16x4*)(P + (size_t)4096 * 768 + f);
    f32x4 x = *(const f32x4*)(X2 + f);
    f32x4 bi = *(const f32x4*)(b2 + col);
    f32x4 o;
#pragma unroll
    for (int i = 0; i < 4; ++i) o[i] = (float)a[i] + (float)b[i] + x[i] + bi[i];
    *(f32x4*)(OUT + f) = o;
}

// ---------------- GEMM (BK=32): QKV + FFN1 ----------------
// Flat grid = GX * Tiles. c=blockIdx&7 (XCD), s=blockIdx>>3: xb=s%GX, tile=(s/GX)*8+c.
// MODE 0: QKV -> q/k scatter bf16 [B,H,S,64]; V written TRANSPOSED [bh][64][2048]
// MODE 2: FFN1 -> bf16 relu(acc + b1)
template <int MODE, int TN, int GX>
__global__ void __launch_bounds__(256)
gemm_kernel(const bf16* __restrict__ A, const bf16* __restrict__ BT,
            int K, int N,
            const float* __restrict__ bias0, const float* __restrict__ bias1,
            const float* __restrict__ bias2,
            void* __restrict__ out0, void* __restrict__ out1, void* __restrict__ out2) {
    constexpr int NJ = TN / 32;
    __shared__ bf16 sA[2][128 * 32];
    __shared__ bf16 sB[2][TN * 32];
    const int tid = threadIdx.x;
    const int lane = tid & 63, wave = tid >> 6;
    const int quad = lane >> 4, l16 = lane & 15;

    const int c = blockIdx.x & 7, sidx = blockIdx.x >> 3;
    const int xb = sidx % GX, tile = (sidx / GX) * 8 + c;
    const int m0 = tile * 128, n0 = xb * TN;
    const int wm = (wave >> 1) * 64, wn = (wave & 1) * (TN / 2);

    const f32x4 zero = {0.f, 0.f, 0.f, 0.f};
    f32x4 acc[4][NJ];
#pragma unroll
    for (int i = 0; i < 4; ++i)
#pragma unroll
        for (int j = 0; j < NJ; ++j) acc[i][j] = zero;

    const int c0 = tid, c1 = tid + 256;
    const int ar0 = m0 + (c0 >> 2), ak0 = (c0 & 3) * 8;
    const int ar1 = m0 + (c1 >> 2), ak1 = (c1 & 3) * 8;
    const int br0 = n0 + (c0 >> 2), br1 = n0 + (c1 >> 2);

    auto stage = [&](int k0, int b) {
        gl_lds16(A + (size_t)ar0 * K + k0 + ak0, &sA[b][c0 * 8]);
        gl_lds16(A + (size_t)ar1 * K + k0 + ak1, &sA[b][c1 * 8]);
        gl_lds16(BT + (size_t)br0 * K + k0 + ak0, &sB[b][c0 * 8]);
        if constexpr (TN * 4 > 256) {
            if (tid < TN * 4 - 256)  // wave-uniform (multiple of 64)
                gl_lds16(BT + (size_t)br1 * K + k0 + ak1, &sB[b][c1 * 8]);
        }
    };
    auto compute = [&](int b) {
        bf16x8 af[4], bfr[NJ];
#pragma unroll
        for (int i = 0; i < 4; ++i)
            af[i] = *(const bf16x8*)&sA[b][(wm + i * 16 + l16) * 32 + quad * 8];
#pragma unroll
        for (int j = 0; j < NJ; ++j)
            bfr[j] = *(const bf16x8*)&sB[b][(wn + j * 16 + l16) * 32 + quad * 8];
#pragma unroll
        for (int i = 0; i < 4; ++i)
#pragma unroll
            for (int j = 0; j < NJ; ++j)
                acc[i][j] = mfma16(af[i], bfr[j], acc[i][j]);
    };

    stage(0, 0);
    for (int k0 = 0; k0 < K; k0 += 64) {
        __syncthreads();
        if (k0 + 32 < K) stage(k0 + 32, 1);
        compute(0);
        __syncthreads();
        if (k0 + 64 < K) stage(k0 + 64, 0);
        compute(1);
    }

#pragma unroll
    for (int i = 0; i < 4; ++i) {
#pragma unroll
        for (int j = 0; j < NJ; ++j) {
            const int col = n0 + wn + j * 16 + l16;
            if (MODE == 0) {
                int mat = col / 768;
                int cc2 = col - mat * 768;
                float bias = (mat == 0 ? bias0 : mat == 1 ? bias1 : bias2)[cc2];
                int h = cc2 >> 6, d = cc2 & 63;
                if (mat == 2) {
                    // V^T store: rows r are s-consecutive -> packed bf16x4
                    int row0 = m0 + wm + i * 16 + quad * 4;
                    int b = row0 >> 11, s0 = row0 & 2047;
                    bf16x4 pv;
#pragma unroll
                    for (int r = 0; r < 4; ++r) pv[r] = (bf16)(acc[i][j][r] + bias);
                    *(bf16x4*)&((bf16*)out2)[(((size_t)b * 12 + h) * 64 + d) * 2048 + s0] = pv;
                } else {
#pragma unroll
                    for (int r = 0; r < 4; ++r) {
                        const int row = m0 + wm + i * 16 + quad * 4 + r;
                        float v = acc[i][j][r] + bias;
                        if (mat == 0) v *= 0.18033688f;  // 0.125*log2(e) folded into q
                        int b = row >> 11, sdx = row & 2047;
                        bf16* dst = (bf16*)(mat == 0 ? out0 : out1);
                        dst[((((size_t)b * 12 + h) * 2048 + sdx) << 6) + d] = (bf16)v;
                    }
                }
            } else {
#pragma unroll
                for (int r = 0; r < 4; ++r) {
                    const int row = m0 + wm + i * 16 + quad * 4 + r;
                    float v = acc[i][j][r] + bias0[col];
                    ((bf16*)out0)[(size_t)row * 3072 + col] = (bf16)fmaxf(v, 0.f);
                }
            }
        }
    }
}

// ---------------- split-K GEMM, BK=64 dbuf, XOR-swizzled LDS ----------------
// OPROJ (K=768) and FFN2 (K=3072), TN=64, bf16 partial out[z][row][col].
// Tiles = 2*(M/128); tile>>1 = m-tile, tile&1 = K-half. 48KB LDS -> 3 blocks/CU.
// Row stride 64 el (128B): XOR chunk swizzle (col_group ^ row&7) keeps frag
// reads 2-way-conflict-free (bank = g*4 pattern, 8 distinct groups/16 lanes).
template <int GX>
__global__ void __launch_bounds__(256)
gemm_k64_kernel(const bf16* __restrict__ A, const bf16* __restrict__ BT,
                int K, int N, bf16* __restrict__ out) {
    __shared__ bf16 sA[2][128 * 64];
    __shared__ bf16 sB[2][64 * 64];
    const int tid = threadIdx.x;
    const int lane = tid & 63, wave = tid >> 6;
    const int quad = lane >> 4, l16 = lane & 15;

    const int c = blockIdx.x & 7, sidx = blockIdx.x >> 3;
    const int xb = sidx % GX, tile = (sidx / GX) * 8 + c;
    const int mt = tile >> 1, zz = tile & 1;
    const int m0 = mt * 128, n0 = xb * 64;
    const int wm = (wave >> 1) * 64, wn = (wave & 1) * 32;

    const f32x4 zero = {0.f, 0.f, 0.f, 0.f};
    f32x4 acc[4][2];
#pragma unroll
    for (int i = 0; i < 4; ++i)
#pragma unroll
        for (int j = 0; j < 2; ++j) acc[i][j] = zero;

    const int kb = zz * (K >> 1), ke = kb + (K >> 1);

    auto stage = [&](int k0, int b) {
#pragma unroll
        for (int cc = 0; cc < 4; ++cc) {
            int ch = tid + cc * 256;
            int r = ch >> 3, dg = (ch & 7) ^ (r & 7);
            gl_lds16(A + (size_t)(m0 + r) * K + k0 + dg * 8, &sA[b][ch * 8]);
        }
#pragma unroll
        for (int cc = 0; cc < 2; ++cc) {
            int ch = tid + cc * 256;
            int r = ch >> 3, dg = (ch & 7) ^ (r & 7);
            gl_lds16(BT + (size_t)(n0 + r) * K + k0 + dg * 8, &sB[b][ch * 8]);
        }
    };
    const int sx = l16 & 7;  // row&7 for all frag rows (wm,wn,i*16 are 0 mod 8)
    auto compute = [&](int b) {
#pragma unroll
        for (int ks = 0; ks < 2; ++ks) {
            bf16x8 af[4], bfr[2];
#pragma unroll
            for (int i = 0; i < 4; ++i)
                af[i] = *(const bf16x8*)&sA[b][(wm + i * 16 + l16) * 64 +
                                              (((ks * 4 + quad) ^ sx) * 8)];
#pragma unroll
            for (int j = 0; j < 2; ++j)
                bfr[j] = *(const bf16x8*)&sB[b][(wn + j * 16 + l16) * 64 +
                                               (((ks * 4 + quad) ^ sx) * 8)];
#pragma unroll
            for (int i = 0; i < 4; ++i)
#pragma unroll
                for (int j = 0; j < 2; ++j)
                    acc[i][j] = mfma16(af[i], bfr[j], acc[i][j]);
        }
    };

    stage(kb, 0);
    // iters: OPROJ 384/64=6, FFN2 1536/64=24 -- both even
    for (int k0 = kb; k0 < ke; k0 += 128) {
        __syncthreads();
        if (k0 + 64 < ke) stage(k0 + 64, 1);
        compute(0);
        __syncthreads();
        if (k0 + 128 < ke) stage(k0 + 128, 0);
        compute(1);
    }

    bf16* o = out + (size_t)zz * 4096 * N;
#pragma unroll
    for (int i = 0; i < 4; ++i) {
#pragma unroll
        for (int j = 0; j < 2; ++j) {
            const int col = n0 + wn + j * 16 + l16;
#pragma unroll
            for (int r = 0; r < 4; ++r) {
                const int row = m0 + wm + i * 16 + quad * 4 + r;
                o[(size_t)row * N + col] = (bf16)acc[i][j][r];
            }
        }
    }
}

// ---------------- flash attention (R9-proven) ----------------
__global__ void __launch_bounds__(256)
attn_kernel(const bf16* __restrict__ Q, const bf16* __restrict__ Kg,
            const bf16* __restrict__ VT, bf16* __restrict__ OP,
            float* __restrict__ LP) {
    const int S = 2048;
    __shared__ bf16 qps[9216];
    __shared__ bf16 ks[2][4096];
    __shared__ bf16 vts[2][4096];

    const int tid = threadIdx.x;
    const int lane = tid & 63, wave = tid >> 6;
    const int quad = lane >> 4, l16 = lane & 15;
    const int half = blockIdx.y, bh = blockIdx.z;
    const int q0 = blockIdx.x * 128;
    const bf16* Qb = Q + (size_t)bh * S * 64;
    const bf16* Kb = Kg + (size_t)bh * S * 64;
    const bf16* VTb = VT + (size_t)bh * 64 * S;

    const int kv_lo = half * (S / 2);

    auto stage = [&](int kv0, int b) {
#pragma unroll
        for (int cc = 0; cc < 2; ++cc) {
            int c = tid + cc * 256;
            int r = c >> 3, dg = (c & 7) ^ (r & 7);
            gl_lds16(Kb + (size_t)(kv0 + r) * 64 + dg * 8, &ks[b][c * 8]);
            gl_lds16(VTb + (size_t)r * S + kv0 + dg * 8, &vts[b][c * 8]);
        }
    };

#pragma unroll
    for (int cc = 0; cc < 4; ++cc) {
        int c = tid + cc * 256;
        int r = c >> 3, dg = (c & 7) ^ (r & 7);
        gl_lds16(Qb + (size_t)(q0 + r) * 64 + dg * 8, &qps[c * 8]);
    }
    stage(kv_lo, 0);
    __syncthreads();

    bf16x8 qf[2][2];
#pragma unroll
    for (int jq = 0; jq < 2; ++jq) {
        int qr = wave * 32 + jq * 16 + l16;
#pragma unroll
        for (int kh = 0; kh < 2; ++kh)
            qf[jq][kh] = *(const bf16x8*)&qps[qr * 64 + (((kh * 4 + quad) ^ (l16 & 7)) * 8)];
    }

    bf16x8 ones;
#pragma unroll
    for (int i = 0; i < 8; ++i) ones[i] = (bf16)1.0f;

    f32x4 oacc[4][2];
    f32x4 lacc[2];
#pragma unroll
    for (int fd = 0; fd < 4; ++fd)
#pragma unroll
        for (int jq = 0; jq < 2; ++jq) oacc[fd][jq] = {0.f, 0.f, 0.f, 0.f};
    lacc[0] = {0.f, 0.f, 0.f, 0.f};
    lacc[1] = {0.f, 0.f, 0.f, 0.f};

    bf16* ps = &qps[wave * 2304];

    auto compute = [&](int b) {
        f32x4 sacc[4][2];
#pragma unroll
        for (int i = 0; i < 4; ++i)
#pragma unroll
            for (int jq = 0; jq < 2; ++jq) sacc[i][jq] = {0.f, 0.f, 0.f, 0.f};
#pragma unroll
        for (int kh = 0; kh < 2; ++kh) {
#pragma unroll
            for (int i = 0; i < 4; ++i) {
                int kr = i * 16 + l16;
                bf16x8 kf = *(const bf16x8*)&ks[b][kr * 64 + (((kh * 4 + quad) ^ (l16 & 7)) * 8)];
                sacc[i][0] = mfma16(kf, qf[0][kh], sacc[i][0]);
                sacc[i][1] = mfma16(kf, qf[1][kh], sacc[i][1]);
            }
        }
#pragma unroll
        for (int jq = 0; jq < 2; ++jq) {
            const int qr = jq * 16 + l16;
#pragma unroll
            for (int i = 0; i < 4; ++i) {
                bf16x4 pk;
#pragma unroll
                for (int r = 0; r < 4; ++r)
                    pk[r] = (bf16)__builtin_amdgcn_exp2f(sacc[i][jq][r]);
                *(bf16x4*)&ps[qr * 72 + i * 16 + quad * 4] = pk;
            }
        }
#pragma unroll
        for (int kh = 0; kh < 2; ++kh) {
            bf16x8 pb0 = *(const bf16x8*)&ps[(0 * 16 + l16) * 72 + kh * 32 + quad * 8];
            bf16x8 pb1 = *(const bf16x8*)&ps[(1 * 16 + l16) * 72 + kh * 32 + quad * 8];
            lacc[0] = mfma16(ones, pb0, lacc[0]);
            lacc[1] = mfma16(ones, pb1, lacc[1]);
#pragma unroll
            for (int fd = 0; fd < 4; ++fd) {
                int dr = fd * 16 + l16;
                bf16x8 vf = *(const bf16x8*)&vts[b][dr * 64 + (((kh * 4 + quad) ^ (l16 & 7)) * 8)];
                oacc[fd][0] = mfma16(vf, pb0, oacc[fd][0]);
                oacc[fd][1] = mfma16(vf, pb1, oacc[fd][1]);
            }
        }
    };

    for (int tt = 0; tt < 8; ++tt) {
        const int t0 = tt * 2;
        __syncthreads();
        if (t0 + 1 < 16) stage(kv_lo + (t0 + 1) * 64, 1);
        compute(0);
        __syncthreads();
        if (t0 + 2 < 16) stage(kv_lo + (t0 + 2) * 64, 0);
        compute(1);
    }

    const size_t rbase = (size_t)half * 24 * S + (size_t)bh * S + q0;
    if (quad == 0) {
#pragma unroll
        for (int jq = 0; jq < 2; ++jq)
            LP[rbase + wave * 32 + jq * 16 + l16] = lacc[jq][0];
    }
    bf16* op = OP + rbase * 64;
#pragma unroll
    for (int jq = 0; jq < 2; ++jq) {
        const int qr = wave * 32 + jq * 16 + l16;
#pragma unroll
        for (int fd = 0; fd < 4; ++fd) {
            bf16x4 ov;
#pragma unroll
            for (int r = 0; r < 4; ++r) ov[r] = (bf16)oacc[fd][jq][r];
            *(bf16x4*)&op[(size_t)qr * 64 + fd * 16 + quad * 4] = ov;
        }
    }
}

// ctx = (O0+O1)/(l0+l1), bf16
__global__ void __launch_bounds__(256)
attn_combine(const bf16* __restrict__ OP, const float* __restrict__ LP,
             bf16* __restrict__ CTX) {
    const int tid = threadIdx.x;
    const size_t r = (size_t)blockIdx.x * 32 + (tid >> 3);
    const int d0 = (tid & 7) * 8;
    const size_t RT = (size_t)24 * 2048;
    float rinv = 1.f / (LP[r] + LP[RT + r]);
    bf16x8 a = *(const bf16x8*)(OP + r * 64 + d0);
    bf16x8 b = *(const bf16x8*)(OP + (RT + r) * 64 + d0);
    int bh = (int)(r >> 11), s = (int)(r & 2047);
    int bb = bh / 12, h = bh - bb * 12;
    bf16x8 out;
#pragma unroll
    for (int i = 0; i < 8; ++i) out[i] = (bf16)(((float)a[i] + (float)b[i]) * rinv);
    *(bf16x8*)&CTX[(size_t)(bb * 2048 + s) * 768 + h * 64 + d0] = out;
}

// ---------------- host launch ----------------
extern "C" void kernel_launch(void* const* d_in, const int* in_sizes, int n_in,
                              void* d_out, int out_size, void* d_ws, size_t ws_size,
                              hipStream_t stream) {
    const int S = 2048, D = 768, F = 3072, M = 4096;
    const float* x = (const float*)d_in[0];
    const float* wq = (const float*)d_in[2];
    const float* bq = (const float*)d_in[3];
    const float* wk = (const float*)d_in[4];
    const float* bk = (const float*)d_in[5];
    const float* wv = (const float*)d_in[6];
    const float* bv = (const float*)d_in[7];
    const float* wo = (const float*)d_in[8];
    const float* bo = (const float*)d_in[9];
    const float* w1 = (const float*)d_in[10];
    const float* b1 = (const float*)d_in[11];
    const float* w2 = (const float*)d_in[12];
    const float* b2 = (const float*)d_in[13];
    const float* alpha1 = (const float*)d_in[14];
    const float* beta1 = (const float*)d_in[15];
    const float* alpha2 = (const float*)d_in[16];
    const float* beta2 = (const float*)d_in[17];

    char* p = (char*)d_ws;
    auto take = [&](size_t n) { char* r = p; p += (n + 255) & ~(size_t)255; return r; };
    bf16* wqkvT = (bf16*)take((size_t)3 * D * D * 2);
    bf16* woT   = (bf16*)take((size_t)D * D * 2);
    bf16* w1T   = (bf16*)take((size_t)F * D * 2);
    bf16* w2T   = (bf16*)take((size_t)D * F * 2);
    bf16* xn    = (bf16*)take((size_t)M * D * 2);
    float* x2   = (float*)take((size_t)M * D * 4);
    bf16* qb    = (bf16*)take((size_t)M * D * 2);
    bf16* kb    = (bf16*)take((size_t)M * D * 2);
    bf16* ctx   = (bf16*)take((size_t)M * D * 2);
    bf16* hb    = qb;  // FFN1 out aliases q (dead after attention)
    bf16* VT    = (bf16*)take((size_t)M * D * 2);   // V^T written directly by QKV
    bf16* op    = (bf16*)take((size_t)2 * M * D * 2);
    float* lp   = (float*)take((size_t)2 * 24 * S * 4);
    bf16* pp    = (bf16*)take((size_t)2 * M * D * 2);

    // prep: 6912 transpose tiles + 4096 LN1 rows in one launch
    prep_kernel<<<dim3(6912 + M), 256, 0, stream>>>(
        wq, wk, wv, wo, w1, w2, wqkvT, woT, w1T, w2T, x, xn, alpha1, beta1);
    // QKV: TM=128 TN=96, tiles=32, GX=24 -> 768 blocks; V written transposed
    gemm_kernel<0, 96, 24><<<dim3(768), 256, 0, stream>>>(
        xn, wqkvT, D, 3 * D, bq, bk, bv, qb, kb, VT);
    attn_kernel<<<dim3(S / 128, 2, 24), 256, 0, stream>>>(qb, kb, VT, op, lp);
    attn_combine<<<dim3(24 * S / 32), 256, 0, stream>>>(op, lp, ctx);
    // OPROJ split-K=2, BK=64: tiles=64, GX=12 -> 768 blocks
    gemm_k64_kernel<12><<<dim3(768), 256, 0, stream>>>(ctx, woT, D, D, pp);
    combine_ln2<<<M, 256, 0, stream>>>(pp, bo, x, x2, xn, alpha2, beta2);
    // FFN1: TM=128 TN=128, tiles=32, GX=24 -> 768 blocks
    gemm_kernel<2, 128, 24><<<dim3(768), 256, 0, stream>>>(
        xn, w1T, D, F, b1, nullptr, nullptr, hb, nullptr, nullptr);
    // FFN2 split-K=2, BK=64: tiles=64, GX=12 -> 768 blocks
    gemm_k64_kernel<12><<<dim3(768), 256, 0, stream>>>(hb, w2T, F, D, pp);
    ffn2_combine<<<dim3(M * D / 1024), 256, 0, stream>>>(pp, b2, x2, (float*)d_out);
}